// Round 5
// baseline (177.361 us; speedup 1.0000x reference)
//
#include <hip/hip_runtime.h>
#include <hip/hip_bf16.h>
#include <stdint.h>
#include <math.h>

#define B_ 2
#define T_ 2048
#define C_ 1024
#define H_ 16
#define HD_ 64
#define BT_ (B_*T_)      // 4096 rows
#define N1_ (3*C_)       // 3072

typedef unsigned short u16;
typedef uint32_t u32;
typedef __attribute__((ext_vector_type(8))) short bf16x8;
typedef __attribute__((ext_vector_type(4))) float f32x4;

__device__ __forceinline__ u16 f2bf(float f) {
  __hip_bfloat16 h = __float2bfloat16(f);
  return *reinterpret_cast<u16*>(&h);
}
__device__ __forceinline__ float bf2f(u16 u) {
  u32 w = ((u32)u) << 16;
  return *reinterpret_cast<float*>(&w);
}

__device__ __forceinline__ void gload_lds16(const void* g, void* l) {
  __builtin_amdgcn_global_load_lds(
      (const __attribute__((address_space(1))) uint32_t*)g,
      (__attribute__((address_space(3))) uint32_t*)l, 16, 0, 0);
}

// ---------------- cast x: fp32 -> bf16 ----------------
__global__ void cast_f32_bf16_k(const float* __restrict__ in, u16* __restrict__ out, int n) {
  int idx = (blockIdx.x * blockDim.x + threadIdx.x) * 4;
  if (idx >= n) return;
  float4 v = *reinterpret_cast<const float4*>(in + idx);
  u16 tmp[4] = {f2bf(v.x), f2bf(v.y), f2bf(v.z), f2bf(v.w)};
  *reinterpret_cast<uint2*>(out + idx) = *reinterpret_cast<const uint2*>(tmp);
}

// ---------------- transpose+cast: w (K x N fp32) -> wt (N x K bf16) ----------------
__global__ void transcast_k(const float* __restrict__ w, u16* __restrict__ wt, int K, int N) {
  __shared__ float tile[32][33];
  int n0 = blockIdx.x * 32, k0 = blockIdx.y * 32;
  int tx = threadIdx.x, ty = threadIdx.y;   // block (32,8)
#pragma unroll
  for (int i = 0; i < 4; i++)
    tile[ty + i*8][tx] = w[(size_t)(k0 + ty + i*8) * N + n0 + tx];
  __syncthreads();
#pragma unroll
  for (int i = 0; i < 4; i++)
    wt[(size_t)(n0 + ty + i*8) * K + k0 + tx] = f2bf(tile[tx][ty + i*8]);
}

// ---------------- GEMM: A (M x K bf16), Bt (N x K bf16) -> C (M x N) ----------------
template<int OUTF32>
__global__ __launch_bounds__(256) void gemm_bt(const u16* __restrict__ A, const u16* __restrict__ Bt,
                                               void* __restrict__ Cv, int M, int N, int K) {
  __shared__ u16 As[128*32];
  __shared__ u16 Bs[128*32];
  int tid = threadIdx.x, wave = tid >> 6, lane = tid & 63;
  int m0 = blockIdx.y * 128, n0 = blockIdx.x * 128;
  int wm = (wave >> 1) * 64, wn = (wave & 1) * 64;
  f32x4 acc[4][4] = {};
  int srow = lane >> 2, scol = (lane & 3) * 8;           // staging: 4 lanes per 32-elem row
  int fro  = (lane & 15) * 32 + (lane >> 4) * 8;         // fragment read offset

  for (int k0 = 0; k0 < K; k0 += 32) {
    __syncthreads();
#pragma unroll
    for (int i = 0; i < 2; i++) {
      gload_lds16(A  + (size_t)(m0 + i*64 + wave*16 + srow) * K + k0 + scol, &As[(i*64 + wave*16) * 32]);
      gload_lds16(Bt + (size_t)(n0 + i*64 + wave*16 + srow) * K + k0 + scol, &Bs[(i*64 + wave*16) * 32]);
    }
    asm volatile("s_waitcnt vmcnt(0)" ::: "memory");
    __syncthreads();
    bf16x8 af[4], bfr[4];
#pragma unroll
    for (int i = 0; i < 4; i++) af[i]  = *reinterpret_cast<const bf16x8*>(&As[(wm + i*16)*32 + fro]);
#pragma unroll
    for (int j = 0; j < 4; j++) bfr[j] = *reinterpret_cast<const bf16x8*>(&Bs[(wn + j*16)*32 + fro]);
#pragma unroll
    for (int i = 0; i < 4; i++)
#pragma unroll
      for (int j = 0; j < 4; j++)
        acc[i][j] = __builtin_amdgcn_mfma_f32_16x16x32_bf16(af[i], bfr[j], acc[i][j], 0, 0, 0);
  }
  int rg = (lane >> 4) * 4, cq = lane & 15;
#pragma unroll
  for (int i = 0; i < 4; i++)
#pragma unroll
    for (int j = 0; j < 4; j++) {
      size_t basei = (size_t)(m0 + wm + i*16 + rg) * N + (size_t)(n0 + wn + j*16 + cq);
#pragma unroll
      for (int r = 0; r < 4; r++) {
        if constexpr (OUTF32) ((float*)Cv)[basei + (size_t)r * N] = acc[i][j][r];
        else                  ((u16*)Cv)[basei + (size_t)r * N]   = f2bf(acc[i][j][r]);
      }
    }
}

// ---------------- causal flash attention ----------------
// qkv: (B*T, 3C) bf16; per head h: Q cols [h*64), K cols [C+h*64), V cols [2C+h*64)
// Grid: (16, B*H). Block = 4 waves, one 128-query strip: strip = 15 - blockIdx.x
// (longest first). Wave w owns queries strip*128 + w*32 .. +31 (2 groups of 16).
// KV tile = 64 keys, double-buffered in LDS; K via pre-swizzled global_load_lds,
// V reg-staged + transposed + swizzled. Single barrier per tile (2-phase pipeline).
// Softmax in exp2 domain (Q pre-scaled by 0.125*log2e); defer-rescale THR=8.
__global__ __launch_bounds__(256) void attn_kernel(const u16* __restrict__ qkv, u16* __restrict__ attnout) {
  __shared__ u16 Ks[2*64*64];    // per buf: row*64 + ((col8*8) ^ ((row&7)<<3))
  __shared__ u16 Vt[2*64*64];    // per buf: d*64 + (key ^ ((d&7)<<3))
  __shared__ u16 Pl[4*32*64];    // per-wave: q*64 + (key ^ ((q&7)<<3))
  int tid = threadIdx.x, wave = tid >> 6, lane = tid & 63;
  int lq = lane & 15, lg = lane >> 4;
  int bh = blockIdx.y, b = bh >> 4, h = bh & 15;
  int strip = 15 - blockIdx.x;            // longest strips dispatched first
  int qbase = strip * 128 + wave * 32;
  const u16* base = qkv + (size_t)b * T_ * N1_;

  // Q fragments pre-scaled by 0.125*log2(e): qf[qs][ch] lane l -> Q[qbase+qs*16+lq][ch*32+lg*8+j]
  const float QSC = 0.125f * 1.44269504088896f;
  bf16x8 qf[2][2];
#pragma unroll
  for (int qs = 0; qs < 2; qs++)
#pragma unroll
    for (int ch = 0; ch < 2; ch++) {
      bf16x8 raw = *reinterpret_cast<const bf16x8*>(
          base + (size_t)(qbase + qs*16 + lq) * N1_ + h*HD_ + ch*32 + lg*8);
      u16* rw = (u16*)&raw;
      u16 tmp[8];
#pragma unroll
      for (int j = 0; j < 8; j++) tmp[j] = f2bf(bf2f(rw[j]) * QSC);
      qf[qs][ch] = *reinterpret_cast<const bf16x8*>(tmp);
    }

  float m_run[2] = {-__builtin_inff(), -__builtin_inff()};
  float l_run[2] = {0.f, 0.f};
  f32x4 oacc[2][4] = {};

  // K staging: chunk c = wave*64+lane (+256); row=c>>3, cb=c&7; source col pre-swizzled
  int kc0 = wave*64 + lane;
  int krow0 = kc0 >> 3, kcb0 = kc0 & 7;
  const u16* ksrc0 = base + (size_t)krow0 * N1_ + C_ + h*HD_ + (kcb0 ^ (krow0 & 7)) * 8;
  int kc1 = kc0 + 256;
  int krow1 = kc1 >> 3, kcb1 = kc1 & 7;
  const u16* ksrc1 = base + (size_t)krow1 * N1_ + C_ + h*HD_ + (kcb1 ^ (krow1 & 7)) * 8;
  // V staging: thread handles keys (2kp, 2kp+1) x d[dc*8..+7]
  int vkp = lane & 31, vdc = wave*2 + (lane >> 5);
  const u16* vsrc = base + (size_t)(2*vkp) * N1_ + 2*C_ + h*HD_ + vdc*8;

  u32* Vt32 = reinterpret_cast<u32*>(Vt);
  int nkt = 2*strip + 2;                  // 64-key tiles needed by this strip

  auto stageK = [&](int kb, int buf) {
    gload_lds16(ksrc0 + (size_t)kb * N1_, (char*)Ks + buf*8192 + wave*1024);
    gload_lds16(ksrc1 + (size_t)kb * N1_, (char*)Ks + buf*8192 + 4096 + wave*1024);
  };
  auto loadV = [&](int kb, bf16x8& va, bf16x8& vb) {
    va = *reinterpret_cast<const bf16x8*>(vsrc + (size_t)kb * N1_);
    vb = *reinterpret_cast<const bf16x8*>(vsrc + (size_t)kb * N1_ + N1_);
  };
  auto writeV = [&](int buf, const bf16x8& va, const bf16x8& vb) {
    const u16* au = (const u16*)&va;
    const u16* bu = (const u16*)&vb;
    u32* dst = Vt32 + buf*2048;
#pragma unroll
    for (int i = 0; i < 8; i++) {
      int d = vdc*8 + i;
      dst[d*32 + (((2*vkp) ^ (i<<3)) >> 1)] = (u32)au[i] | ((u32)bu[i] << 16);
    }
  };

  // prologue: stage tile 0 into buf 0
  bf16x8 va, vb;
  stageK(0, 0);
  loadV(0, va, vb);
  asm volatile("s_waitcnt vmcnt(0)" ::: "memory");
  writeV(0, va, vb);
  __syncthreads();

  int cur = 0;
  for (int kt = 0; kt < nkt; kt++) {
    int kb = kt * 64;
    bool nxt = (kt + 1 < nkt);
    if (nxt) {                            // issue next tile's loads before compute
      stageK(kb + 64, cur ^ 1);
      loadV(kb + 64, va, vb);
    }

    if (kb <= qbase + 31) {               // wave-uniform skip of fully-masked tiles
      const u16* ksb = &Ks[cur * 4096];
      const u16* vtb = &Vt[cur * 4096];
      // ---- QK^T (pre-scaled to log2 domain): S^T[key][q] ----
      f32x4 st[2][4];
#pragma unroll
      for (int sub = 0; sub < 4; sub++) {
        int krow = sub*16 + lq;
        bf16x8 kf0 = *reinterpret_cast<const bf16x8*>(&ksb[krow*64 + ((lg*8)      ^ ((lq&7)<<3))]);
        bf16x8 kf1 = *reinterpret_cast<const bf16x8*>(&ksb[krow*64 + ((32 + lg*8) ^ ((lq&7)<<3))]);
#pragma unroll
        for (int qs = 0; qs < 2; qs++) {
          f32x4 z = {0.f, 0.f, 0.f, 0.f};
          z = __builtin_amdgcn_mfma_f32_16x16x32_bf16(kf0, qf[qs][0], z, 0, 0, 0);
          z = __builtin_amdgcn_mfma_f32_16x16x32_bf16(kf1, qf[qs][1], z, 0, 0, 0);
          st[qs][sub] = z;
        }
      }
      // ---- online softmax (exp2 domain), defer-rescale THR=8 ----
#pragma unroll
      for (int qs = 0; qs < 2; qs++) {
        int qg = qbase + qs*16 + lq;
        float sc[4][4];
        float tmax = -__builtin_inff();
#pragma unroll
        for (int sub = 0; sub < 4; sub++)
#pragma unroll
          for (int r = 0; r < 4; r++) {
            float s = st[qs][sub][r];
            int keyg = kb + sub*16 + lg*4 + r;
            if (keyg > qg) s = -__builtin_inff();
            sc[sub][r] = s;
            tmax = fmaxf(tmax, s);
          }
        tmax = fmaxf(tmax, __shfl_xor(tmax, 16));
        tmax = fmaxf(tmax, __shfl_xor(tmax, 32));
        if (!__all(tmax <= m_run[qs] + 8.f)) {
          float mnew = fmaxf(m_run[qs], tmax);
          float rs = exp2f(m_run[qs] - mnew);
          l_run[qs] *= rs;
          m_run[qs] = mnew;
          float rq[4];
#pragma unroll
          for (int r = 0; r < 4; r++) rq[r] = __shfl(rs, lg*4 + r);
#pragma unroll
          for (int dt = 0; dt < 4; dt++)
#pragma unroll
            for (int r = 0; r < 4; r++) oacc[qs][dt][r] *= rq[r];
        }
        float tsum = 0.f;
        int qloc = qs*16 + lq;
#pragma unroll
        for (int sub = 0; sub < 4; sub++)
#pragma unroll
          for (int t2 = 0; t2 < 2; t2++) {
            float p0 = exp2f(sc[sub][2*t2]   - m_run[qs]);
            float p1 = exp2f(sc[sub][2*t2+1] - m_run[qs]);
            tsum += p0 + p1;
            int key0 = sub*16 + lg*4 + 2*t2;
            int el = qloc*64 + (key0 ^ ((lq&7)<<3));
            reinterpret_cast<u32*>(Pl)[wave*1024 + (el >> 1)] = (u32)f2bf(p0) | ((u32)f2bf(p1) << 16);
          }
        tsum += __shfl_xor(tsum, 16);
        tsum += __shfl_xor(tsum, 32);
        l_run[qs] += tsum;
      }
      // ---- O += P * V ----
#pragma unroll
      for (int ks = 0; ks < 2; ks++) {
        int kcol = (ks*32 + lg*8) ^ ((lq&7)<<3);
        bf16x8 pa0 = *reinterpret_cast<const bf16x8*>(&Pl[wave*2048 + lq*64      + kcol]);
        bf16x8 pa1 = *reinterpret_cast<const bf16x8*>(&Pl[wave*2048 + (16+lq)*64 + kcol]);
#pragma unroll
        for (int dt = 0; dt < 4; dt++) {
          bf16x8 vf = *reinterpret_cast<const bf16x8*>(&vtb[(dt*16 + lq)*64 + kcol]);
          oacc[0][dt] = __builtin_amdgcn_mfma_f32_16x16x32_bf16(pa0, vf, oacc[0][dt], 0, 0, 0);
          oacc[1][dt] = __builtin_amdgcn_mfma_f32_16x16x32_bf16(pa1, vf, oacc[1][dt], 0, 0, 0);
        }
      }
    }

    if (nxt) {                            // land next tile's V into the other buffer
      asm volatile("s_waitcnt vmcnt(0)" ::: "memory");
      writeV(cur ^ 1, va, vb);
    }
    __syncthreads();
    cur ^= 1;
  }

  // ---- epilogue ----
#pragma unroll
  for (int qs = 0; qs < 2; qs++) {
    float linv[4];
#pragma unroll
    for (int r = 0; r < 4; r++) linv[r] = 1.f / __shfl(l_run[qs], lg*4 + r);
#pragma unroll
    for (int dt = 0; dt < 4; dt++)
#pragma unroll
      for (int r = 0; r < 4; r++) {
        size_t row = (size_t)(b*T_ + qbase + qs*16 + lg*4 + r);
        attnout[row * C_ + h*HD_ + dt*16 + lq] = f2bf(oacc[qs][dt][r] * linv[r]);
      }
  }
}

extern "C" void kernel_launch(void* const* d_in, const int* in_sizes, int n_in,
                              void* d_out, int out_size, void* d_ws, size_t ws_size,
                              hipStream_t stream) {
  const float* x     = (const float*)d_in[0];
  const float* w_qkv = (const float*)d_in[1];
  const float* w_out = (const float*)d_in[2];
  float* out = (float*)d_out;
  char* ws = (char*)d_ws;
  u16* xb    = (u16*)(ws);                         // 8 MB  : x bf16 (4096 x 1024)
  u16* wqkvT = (u16*)(ws + ((size_t)8  << 20));    // 6 MB  : w_qkv^T bf16 (3072 x 1024)
  u16* woutT = (u16*)(ws + ((size_t)14 << 20));    // 2 MB  : w_out^T bf16 (1024 x 1024)
  u16* qkvb  = (u16*)(ws + ((size_t)16 << 20));    // 24 MB : qkv bf16 (4096 x 3072)
  u16* attnb = (u16*)(ws + ((size_t)40 << 20));    // 8 MB  : attn out bf16 (4096 x 1024)

  cast_f32_bf16_k<<<(BT_*C_)/1024, 256, 0, stream>>>(x, xb, BT_*C_);
  transcast_k<<<dim3(N1_/32, C_/32), dim3(32, 8), 0, stream>>>(w_qkv, wqkvT, C_, N1_);
  transcast_k<<<dim3(C_/32, C_/32), dim3(32, 8), 0, stream>>>(w_out, woutT, C_, C_);
  gemm_bt<0><<<dim3(N1_/128, BT_/128), 256, 0, stream>>>(xb, wqkvT, (void*)qkvb, BT_, N1_, C_);
  attn_kernel<<<dim3(16, B_*H_), 256, 0, stream>>>(qkvb, attnb);
  gemm_bt<1><<<dim3(C_/128, BT_/128), 256, 0, stream>>>(attnb, woutT, (void*)out, BT_, C_, C_);
}

// Round 6
// 160.864 us; speedup vs baseline: 1.1026x; 1.1026x over previous
//
#include <hip/hip_runtime.h>
#include <hip/hip_bf16.h>
#include <stdint.h>
#include <math.h>

#define B_ 2
#define T_ 2048
#define C_ 1024
#define H_ 16
#define HD_ 64
#define BT_ (B_*T_)      // 4096 rows
#define N1_ (3*C_)       // 3072

typedef unsigned short u16;
typedef uint32_t u32;
typedef __attribute__((ext_vector_type(8))) short bf16x8;
typedef __attribute__((ext_vector_type(4))) float f32x4;
typedef __attribute__((ext_vector_type(16))) float f32x16;
typedef __attribute__((ext_vector_type(4))) unsigned int u32x4;

__device__ __forceinline__ u16 f2bf(float f) {
  __hip_bfloat16 h = __float2bfloat16(f);
  return *reinterpret_cast<u16*>(&h);
}
__device__ __forceinline__ float bf2f(u16 u) {
  u32 w = ((u32)u) << 16;
  return *reinterpret_cast<float*>(&w);
}

__device__ __forceinline__ void gload_lds16(const void* g, void* l) {
  __builtin_amdgcn_global_load_lds(
      (const __attribute__((address_space(1))) uint32_t*)g,
      (__attribute__((address_space(3))) uint32_t*)l, 16, 0, 0);
}

// ---------------- cast x: fp32 -> bf16 ----------------
__global__ void cast_f32_bf16_k(const float* __restrict__ in, u16* __restrict__ out, int n) {
  int idx = (blockIdx.x * blockDim.x + threadIdx.x) * 4;
  if (idx >= n) return;
  float4 v = *reinterpret_cast<const float4*>(in + idx);
  u16 tmp[4] = {f2bf(v.x), f2bf(v.y), f2bf(v.z), f2bf(v.w)};
  *reinterpret_cast<uint2*>(out + idx) = *reinterpret_cast<const uint2*>(tmp);
}

// ---------------- transpose+cast: w (K x N fp32) -> wt (N x K bf16) ----------------
__global__ void transcast_k(const float* __restrict__ w, u16* __restrict__ wt, int K, int N) {
  __shared__ float tile[32][33];
  int n0 = blockIdx.x * 32, k0 = blockIdx.y * 32;
  int tx = threadIdx.x, ty = threadIdx.y;   // block (32,8)
#pragma unroll
  for (int i = 0; i < 4; i++)
    tile[ty + i*8][tx] = w[(size_t)(k0 + ty + i*8) * N + n0 + tx];
  __syncthreads();
#pragma unroll
  for (int i = 0; i < 4; i++)
    wt[(size_t)(n0 + ty + i*8) * K + k0 + tx] = f2bf(tile[tx][ty + i*8]);
}

// ---------------- GEMM: A (M x K bf16), Bt (N x K bf16) -> C (M x N) ----------------
template<int OUTF32>
__global__ __launch_bounds__(256) void gemm_bt(const u16* __restrict__ A, const u16* __restrict__ Bt,
                                               void* __restrict__ Cv, int M, int N, int K) {
  __shared__ u16 As[128*32];
  __shared__ u16 Bs[128*32];
  int tid = threadIdx.x, wave = tid >> 6, lane = tid & 63;
  int m0 = blockIdx.y * 128, n0 = blockIdx.x * 128;
  int wm = (wave >> 1) * 64, wn = (wave & 1) * 64;
  f32x4 acc[4][4] = {};
  int srow = lane >> 2, scol = (lane & 3) * 8;
  int fro  = (lane & 15) * 32 + (lane >> 4) * 8;

  for (int k0 = 0; k0 < K; k0 += 32) {
    __syncthreads();
#pragma unroll
    for (int i = 0; i < 2; i++) {
      gload_lds16(A  + (size_t)(m0 + i*64 + wave*16 + srow) * K + k0 + scol, &As[(i*64 + wave*16) * 32]);
      gload_lds16(Bt + (size_t)(n0 + i*64 + wave*16 + srow) * K + k0 + scol, &Bs[(i*64 + wave*16) * 32]);
    }
    asm volatile("s_waitcnt vmcnt(0)" ::: "memory");
    __syncthreads();
    bf16x8 af[4], bfr[4];
#pragma unroll
    for (int i = 0; i < 4; i++) af[i]  = *reinterpret_cast<const bf16x8*>(&As[(wm + i*16)*32 + fro]);
#pragma unroll
    for (int j = 0; j < 4; j++) bfr[j] = *reinterpret_cast<const bf16x8*>(&Bs[(wn + j*16)*32 + fro]);
#pragma unroll
    for (int i = 0; i < 4; i++)
#pragma unroll
      for (int j = 0; j < 4; j++)
        acc[i][j] = __builtin_amdgcn_mfma_f32_16x16x32_bf16(af[i], bfr[j], acc[i][j], 0, 0, 0);
  }
  int rg = (lane >> 4) * 4, cq = lane & 15;
#pragma unroll
  for (int i = 0; i < 4; i++)
#pragma unroll
    for (int j = 0; j < 4; j++) {
      size_t basei = (size_t)(m0 + wm + i*16 + rg) * N + (size_t)(n0 + wn + j*16 + cq);
#pragma unroll
      for (int r = 0; r < 4; r++) {
        if constexpr (OUTF32) ((float*)Cv)[basei + (size_t)r * N] = acc[i][j][r];
        else                  ((u16*)Cv)[basei + (size_t)r * N]   = f2bf(acc[i][j][r]);
      }
    }
}

// ---------------- causal flash attention: 1 wave / block, no barriers ----------------
// qkv: (B*T, 3C) bf16; per head h: Q cols [h*64), K cols [C+h*64), V cols [2C+h*64)
// 2048 blocks of 64 threads. Each wave owns 32 queries (strip). 32x32x16 MFMA,
// swapped QK^T (S^T = K*Q^T): lane owns query col = lane&31; hi = lane>>5 splits keys.
// K staged via pre-swizzled global_load_lds; V reg-staged -> transposed+swizzled LDS.
// P stays in registers (pack bf16 + shfl_xor(32) half-exchange). O accumulated as O^T.
__global__ __launch_bounds__(64) void attn_kernel(const u16* __restrict__ qkv, u16* __restrict__ attnout) {
  __shared__ u16 Ks[64*64];   // (key,d): elem = key*64 + ((c ^ (key&7))*8 + j), d=8c+j
  __shared__ u16 Vt[64*64];   // (d,key): elem = d*64 + ((kc ^ (d&7))*8 + kj), key=8kc+kj
  int lane = threadIdx.x;
  int q31 = lane & 31, hi = lane >> 5;
  // XCD-aware remap: each XCD serves 4 heads (2MB K/V -> fits 4MB L2); longest strips first
  int lid = blockIdx.x + 64 * blockIdx.y;
  int xcd = lid & 7, idx = lid >> 3;
  int bh = xcd * 4 + (idx & 3);
  int strip = 63 - (idx >> 2);
  int b = bh >> 4, h = bh & 15;
  int qbase = strip * 32;
  int qg = qbase + q31;
  const u16* base = qkv + (size_t)b * T_ * N1_;

  // Q fragments pre-scaled by 0.125*log2(e): qf[kk] = Q[qg][16kk+8hi .. +7]
  const float QSC = 0.125f * 1.44269504088896f;
  bf16x8 qf[4];
  {
    const u16* qrow = base + (size_t)qg * N1_ + h * HD_;
#pragma unroll
    for (int kk = 0; kk < 4; kk++) {
      bf16x8 raw = *reinterpret_cast<const bf16x8*>(qrow + kk*16 + hi*8);
      const u16* rp = (const u16*)&raw;
      u32x4 qp;
#pragma unroll
      for (int j = 0; j < 4; j++)
        qp[j] = (u32)f2bf(bf2f(rp[2*j]) * QSC) | ((u32)f2bf(bf2f(rp[2*j+1]) * QSC) << 16);
      qf[kk] = __builtin_bit_cast(bf16x8, qp);
    }
  }

  // K staging: lane covers key = 8r + (lane>>3), slot = lane&7 -> global c = slot ^ (key&7)
  const u16* ksrc = base + C_ + h*HD_ + (size_t)(lane >> 3) * N1_
                    + (size_t)((((lane & 7) ^ ((lane >> 3) & 7))) * 8);
  // V staging: lane covers keys (2kp, 2kp+1), d-chunks (hi + 2r)*8
  int kp = q31;
  const u16* vsrc = base + 2*C_ + h*HD_ + (size_t)(2*kp) * N1_ + hi*8;
  u32* Vt32 = reinterpret_cast<u32*>(Vt);

  f32x16 oacc[2] = {};           // O^T: row d = (reg&3)+8(reg>>2)+4hi (+32dt), col q = q31
  float m_run = -__builtin_inff(), l_run = 0.f;
  int nkt = (qbase >> 6) + 1;    // 64-key tiles this strip needs

  bf16x8 vA[4], vB[4];
  // ---- prologue: stage tile 0 ----
#pragma unroll
  for (int r = 0; r < 8; r++)
    gload_lds16(ksrc + (size_t)(8*r) * N1_, (char*)Ks + r*1024);
#pragma unroll
  for (int r = 0; r < 4; r++) {
    vA[r] = *reinterpret_cast<const bf16x8*>(vsrc + r*16);
    vB[r] = *reinterpret_cast<const bf16x8*>(vsrc + r*16 + N1_);
  }
  asm volatile("s_waitcnt vmcnt(0)" ::: "memory");
  __builtin_amdgcn_sched_barrier(0);
#pragma unroll
  for (int r = 0; r < 4; r++) {
    const u16* au = (const u16*)&vA[r];
    const u16* bu = (const u16*)&vB[r];
#pragma unroll
    for (int i = 0; i < 8; i++) {
      int d = (hi + 2*r)*8 + i;
      Vt32[d*32 + (((kp>>2) ^ (d&7)) << 2) + (kp&3)] = (u32)au[i] | ((u32)bu[i] << 16);
    }
  }

  for (int kt = 0; kt < nkt; kt++) {
    int kb = kt * 64;
    bool nxt = (kt + 1 < nkt);
    // ---- QK^T: st[ks] = S^T (rows=keys 32ks.., cols=queries), accumulate over d ----
    f32x16 st[2];
#pragma unroll
    for (int ks = 0; ks < 2; ks++) {
      f32x16 z = {};
#pragma unroll
      for (int kk = 0; kk < 4; kk++) {
        bf16x8 kf = *reinterpret_cast<const bf16x8*>(
            &Ks[(32*ks + q31)*64 + ((((kk<<1) | hi) ^ (q31 & 7)) << 3)]);
        z = __builtin_amdgcn_mfma_f32_32x32x16_bf16(kf, qf[kk], z, 0, 0, 0);
      }
      st[ks] = z;
    }
    asm volatile("s_waitcnt lgkmcnt(0)" ::: "memory");   // Ks reads retired
    __builtin_amdgcn_sched_barrier(0);

    // ---- prefetch next tile: K -> LDS (overwrite ok), V -> regs ----
    if (nxt) {
      size_t off = (size_t)(kb + 64) * N1_;
#pragma unroll
      for (int r = 0; r < 4; r++) {
        vA[r] = *reinterpret_cast<const bf16x8*>(vsrc + off + r*16);
        vB[r] = *reinterpret_cast<const bf16x8*>(vsrc + off + r*16 + N1_);
      }
#pragma unroll
      for (int r = 0; r < 8; r++)
        gload_lds16(ksrc + off + (size_t)(8*r) * N1_, (char*)Ks + r*1024);
    }

    // ---- online softmax (exp2 domain, lane-local q), defer-rescale THR=8 ----
    float tmax = -__builtin_inff();
#pragma unroll
    for (int ks = 0; ks < 2; ks++)
#pragma unroll
      for (int r = 0; r < 16; r++) {
        int keyg = kb + 32*ks + (r&3) + 8*(r>>2) + 4*hi;
        float s = (keyg > qg) ? -__builtin_inff() : st[ks][r];
        st[ks][r] = s;
        tmax = fmaxf(tmax, s);
      }
    tmax = fmaxf(tmax, __shfl_xor(tmax, 32));
    if (!__all(tmax <= m_run + 8.f)) {
      float mnew = fmaxf(m_run, tmax);
      float rs = exp2f(m_run - mnew);
      l_run *= rs;
      m_run = mnew;
#pragma unroll
      for (int dt = 0; dt < 2; dt++)
#pragma unroll
        for (int r = 0; r < 16; r++) oacc[dt][r] *= rs;
    }
    float tsum = 0.f;
#pragma unroll
    for (int ks = 0; ks < 2; ks++)
#pragma unroll
      for (int r = 0; r < 16; r++) {
        float p = exp2f(st[ks][r] - m_run);
        st[ks][r] = p;
        tsum += p;
      }
    l_run += tsum + __shfl_xor(tsum, 32);

    // ---- P pack + half-wave exchange + PV (O^T += V^T * P^T) ----
#pragma unroll
    for (int ks = 0; ks < 2; ks++) {
      u32 pk[8], rc[8];
#pragma unroll
      for (int m = 0; m < 8; m++)
        pk[m] = (u32)f2bf(st[ks][2*m]) | ((u32)f2bf(st[ks][2*m+1]) << 16);
#pragma unroll
      for (int m = 0; m < 8; m++)
        rc[m] = (u32)__shfl_xor((int)pk[m], 32);
      u32x4 fr0 = { hi ? rc[2] : pk[0], hi ? rc[3] : pk[1], hi ? pk[2] : rc[0], hi ? pk[3] : rc[1] };
      u32x4 fr1 = { hi ? rc[6] : pk[4], hi ? rc[7] : pk[5], hi ? pk[6] : rc[4], hi ? pk[7] : rc[5] };
#pragma unroll
      for (int kk = 0; kk < 2; kk++) {
        bf16x8 pf = __builtin_bit_cast(bf16x8, kk ? fr1 : fr0);
#pragma unroll
        for (int dt = 0; dt < 2; dt++) {
          bf16x8 vf = *reinterpret_cast<const bf16x8*>(
              &Vt[(32*dt + q31)*64 + ((((ks<<2) | (kk<<1) | hi) ^ (q31 & 7)) << 3)]);
          oacc[dt] = __builtin_amdgcn_mfma_f32_32x32x16_bf16(vf, pf, oacc[dt], 0, 0, 0);
        }
      }
    }
    asm volatile("s_waitcnt lgkmcnt(0)" ::: "memory");   // Vt reads retired
    __builtin_amdgcn_sched_barrier(0);
    if (nxt) {
      asm volatile("s_waitcnt vmcnt(0)" ::: "memory");   // K landed in LDS, V in regs
      __builtin_amdgcn_sched_barrier(0);
#pragma unroll
      for (int r = 0; r < 4; r++) {
        const u16* au = (const u16*)&vA[r];
        const u16* bu = (const u16*)&vB[r];
#pragma unroll
        for (int i = 0; i < 8; i++) {
          int d = (hi + 2*r)*8 + i;
          Vt32[d*32 + (((kp>>2) ^ (d&7)) << 2) + (kp&3)] = (u32)au[i] | ((u32)bu[i] << 16);
        }
      }
    }
  }

  // ---- epilogue: divide by l (lane-local), write O (q = q31 row, d from regs) ----
  float linv = 1.f / l_run;
  u16* orow = attnout + (size_t)(b*T_ + qg) * C_ + h*HD_;
#pragma unroll
  for (int dt = 0; dt < 2; dt++)
#pragma unroll
    for (int m = 0; m < 8; m++) {
      int d = 32*dt + 2*(m&1) + 8*(m>>1) + 4*hi;
      u32 v = (u32)f2bf(oacc[dt][2*m] * linv) | ((u32)f2bf(oacc[dt][2*m+1] * linv) << 16);
      *reinterpret_cast<u32*>(orow + d) = v;
    }
}

extern "C" void kernel_launch(void* const* d_in, const int* in_sizes, int n_in,
                              void* d_out, int out_size, void* d_ws, size_t ws_size,
                              hipStream_t stream) {
  const float* x     = (const float*)d_in[0];
  const float* w_qkv = (const float*)d_in[1];
  const float* w_out = (const float*)d_in[2];
  float* out = (float*)d_out;
  char* ws = (char*)d_ws;
  u16* xb    = (u16*)(ws);                         // 8 MB  : x bf16 (4096 x 1024)
  u16* wqkvT = (u16*)(ws + ((size_t)8  << 20));    // 6 MB  : w_qkv^T bf16 (3072 x 1024)
  u16* woutT = (u16*)(ws + ((size_t)14 << 20));    // 2 MB  : w_out^T bf16 (1024 x 1024)
  u16* qkvb  = (u16*)(ws + ((size_t)16 << 20));    // 24 MB : qkv bf16 (4096 x 3072)
  u16* attnb = (u16*)(ws + ((size_t)40 << 20));    // 8 MB  : attn out bf16 (4096 x 1024)

  cast_f32_bf16_k<<<(BT_*C_)/1024, 256, 0, stream>>>(x, xb, BT_*C_);
  transcast_k<<<dim3(N1_/32, C_/32), dim3(32, 8), 0, stream>>>(w_qkv, wqkvT, C_, N1_);
  transcast_k<<<dim3(C_/32, C_/32), dim3(32, 8), 0, stream>>>(w_out, woutT, C_, C_);
  gemm_bt<0><<<dim3(N1_/128, BT_/128), 256, 0, stream>>>(xb, wqkvT, (void*)qkvb, BT_, N1_, C_);
  attn_kernel<<<dim3(64, 32), 64, 0, stream>>>(qkvb, attnb);
  gemm_bt<1><<<dim3(C_/128, BT_/128), 256, 0, stream>>>(attnb, woutT, (void*)out, BT_, C_, C_);
}